// Round 14
// baseline (64.368 us; speedup 1.0000x reference)
//
#include <hip/hip_runtime.h>
#include <math.h>

#define LWT 512
#define NWT 64
#define BB 4
#define SBASE 16
#define BLK 128        // t's per block in fused_out
#define HALO 132       // BLK + 4 conv halo

// ws layout (floats): sarr [0,BT) | wtT [+32768) | s1g [+4*8320)

// XLA algsimp: x/44100 -> x * RN32(1/44100); *512 folds exactly (pow2), so
// increment = RN32(p * C), C = RN32(512/44100). asm barrier forces the product
// to be ROUNDED before the consuming add (blocks -ffp-contract=fast fusion).
#define INC_C ((float)(512.0 / 44100.0))

__device__ __forceinline__ float inc_mul(float p) {
  float v = p * INC_C;
  asm volatile("" : "+v"(v));
  return v;
}
__device__ __forceinline__ float inc_of(const float* p, int t) { return inc_mul(p[t]); }

// ---- Kernel A: level-0 local scans (fully parallel) + folded wt transpose ----
__global__ void __launch_bounds__(256) scan_level0(const float* __restrict__ pitch,
                                                   float* __restrict__ sarr,
                                                   float* __restrict__ s1g,
                                                   const float* __restrict__ wt,
                                                   float* __restrict__ wtT,
                                                   int T, int NB1) {
  if (blockIdx.y == BB) {  // folded transpose row
    int i = blockIdx.x * blockDim.x + threadIdx.x;
    if (i < NWT * LWT) {
      int n = i >> 9, c = i & 511;
      wtT[c * NWT + n] = wt[i];
    }
    return;
  }
  int k = blockIdx.x * blockDim.x + threadIdx.x;
  int b = blockIdx.y;
  if (k >= NB1) return;
  const float* prow = pitch + (size_t)b * T;
  float* srow = sarr + (size_t)b * T;
  int t0 = k * SBASE;
  float run = 0.0f;
  if (t0 + SBASE <= T) {
    const float4* p4 = reinterpret_cast<const float4*>(prow + t0);
    float4* s4o = reinterpret_cast<float4*>(srow + t0);
#pragma unroll
    for (int i = 0; i < 4; ++i) {
      float4 v = p4[i];
      float4 o;
      run += inc_mul(v.x); o.x = run;
      run += inc_mul(v.y); o.y = run;
      run += inc_mul(v.z); o.z = run;
      run += inc_mul(v.w); o.w = run;
      s4o[i] = o;
    }
  } else {
    for (int t = t0; t < T; ++t) { run += inc_of(prow, t); srow[t] = run; }
  }
  s1g[(size_t)b * NB1 + k] = run;
}

// ---- Kernel B: levels 1..4 + combines, per row, s1 in LDS ----
__global__ void __launch_bounds__(1024) scan_upper(float* __restrict__ s1g, int NB1) {
  int b = blockIdx.x;
  int tid = threadIdx.x;
  float* s1r = s1g + (size_t)b * NB1;
  __shared__ float s1[8320];
  __shared__ float s2[544];
  __shared__ float s3[48];
  __shared__ float s4[16];
  const int NB2 = (NB1 + SBASE - 1) / SBASE;
  const int NB3 = (NB2 + SBASE - 1) / SBASE;
  const int NB4 = (NB3 + SBASE - 1) / SBASE;

  for (int a = tid; a < NB1; a += 1024) s1[a] = s1r[a];
  __syncthreads();
  for (int k = tid; k < NB2; k += 1024) {
    int a0 = k * SBASE, a1 = a0 + SBASE < NB1 ? a0 + SBASE : NB1;
    float run = 0.0f;
    for (int a = a0; a < a1; ++a) { run += s1[a]; s1[a] = run; }
    s2[k] = run;
  }
  __syncthreads();
  for (int k = tid; k < NB3; k += 1024) {
    int a0 = k * SBASE, a1 = a0 + SBASE < NB2 ? a0 + SBASE : NB2;
    float run = 0.0f;
    for (int a = a0; a < a1; ++a) { run += s2[a]; s2[a] = run; }
    s3[k] = run;
  }
  __syncthreads();
  for (int k = tid; k < NB4; k += 1024) {
    int a0 = k * SBASE, a1 = a0 + SBASE < NB3 ? a0 + SBASE : NB3;
    float run = 0.0f;
    for (int a = a0; a < a1; ++a) { run += s3[a]; s3[a] = run; }
    s4[k] = run;
  }
  __syncthreads();
  if (tid == 0) { float r = 0.0f; for (int a = 0; a < NB4; ++a) { r += s4[a]; s4[a] = r; } }
  __syncthreads();
  for (int a = tid; a < NB3; a += 1024)
    if (a >= SBASE) s3[a] = s3[a] + s4[a / SBASE - 1];
  __syncthreads();
  for (int a = tid; a < NB2; a += 1024)
    if (a >= SBASE) s2[a] = s2[a] + s3[a / SBASE - 1];
  __syncthreads();
  for (int a = tid; a < NB1; a += 1024) {
    float v = s1[a];
    if (a >= SBASE) v = v + s2[a / SBASE - 1];
    s1r[a] = v;
  }
}

// Wave64 reduction on the VALU pipe (DPP): xor1, xor2 (quad_perm),
// row_half_mirror, row_mirror, bcast15 (rows 1&3), bcast31 (rows 2&3);
// full sum in lanes 48-63; readlane(63) broadcasts.
__device__ __forceinline__ float dpp_reduce_add(float x) {
  x += __int_as_float(__builtin_amdgcn_update_dpp(0, __float_as_int(x), 0xB1, 0xf, 0xf, true));
  x += __int_as_float(__builtin_amdgcn_update_dpp(0, __float_as_int(x), 0x4E, 0xf, 0xf, true));
  x += __int_as_float(__builtin_amdgcn_update_dpp(0, __float_as_int(x), 0x141, 0xf, 0xf, true));
  x += __int_as_float(__builtin_amdgcn_update_dpp(0, __float_as_int(x), 0x140, 0xf, 0xf, true));
  x += __int_as_float(__builtin_amdgcn_update_dpp(0, __float_as_int(x), 0x142, 0xa, 0xf, true));
  x += __int_as_float(__builtin_amdgcn_update_dpp(0, __float_as_int(x), 0x143, 0xc, 0xf, true));
  return __int_as_float(__builtin_amdgcn_readlane(__float_as_int(x), 63));
}

// ---- Fused: finalize(idx) + att_pre + conv + softmax + einsum + amp ----
// 512 threads, BLK=128 t's per block. B-major LDS staging (conflict-free
// writes; hot-loop reads are wave-uniform broadcasts).
__global__ void __launch_bounds__(512) fused_out(
    const float* __restrict__ pitch, const float* __restrict__ sarr,
    const float* __restrict__ s1g, const float* __restrict__ y,
    const float* __restrict__ amp, const float* __restrict__ wtT,
    const float* __restrict__ cw, const float* __restrict__ cb,
    float* __restrict__ out, int T, int NB1) {
  __shared__ float lds_att[HALO][64];   // 33.8 KB
  __shared__ unsigned ilh_l[BB][HALO];  // il | ih<<16
  __shared__ float alf_l[BB][HALO];
  __shared__ float y_l[BB][HALO];
  __shared__ float amp_l[BB][HALO];
  __shared__ float out_l[BB][BLK];
  int t0 = blockIdx.x * BLK;
  int wid = threadIdx.x >> 6, lane = threadIdx.x & 63;

  // ---- Stage A: waves 0-7 -> (b = wid&3, i-half = wid>>2) ----
  {
    int b = wid & 3;
    for (int i = (wid >> 2) * 64 + lane; i < HALO; i += 128) {
      int t = t0 - 2 + i;
      if (t >= 0 && t < T) {
        float S = sarr[(size_t)b * T + t];
        if (t >= SBASE) S = S + s1g[b * NB1 + (t >> 4) - 1];
        float iv = S - inc_of(pitch, t);   // row-0 increment, folded constant
        // exact mod 512 (== fmodf+fixup bits; q exact pow2 scale, one fma rnd)
        float q = iv * (1.0f / 512.0f);
        float k = floorf(q);
        iv = fmaf(-k, 512.0f, iv);
        float fl = floorf(iv);
        float alpha = iv - fl;              // exact (Sterbenz)
        int ili = (int)fl; if (ili > 511) ili = 511;   // jnp.take clip
        int ihi = ((int)ceilf(iv)) & 511;              // ceil 512 wraps to 0
        ilh_l[b][i] = (unsigned)ili | ((unsigned)ihi << 16);
        alf_l[b][i] = alpha;
        y_l[b][i] = y[(size_t)b * T + t];
        amp_l[b][i] = amp[(size_t)b * T + t];
      }
    }
  }
  __syncthreads();

  // ---- Stage B: att_pre ----
  for (int i = wid; i < HALO; i += 8) {
    int t = t0 - 2 + i;
    float acc = 0.0f;
    if (t >= 0 && t < T) {
#pragma unroll
      for (int b = 0; b < BB; ++b) {
        unsigned st = ilh_l[b][i];
        int ili = st & 0xffff, ihi = st >> 16;
        float alpha = alf_l[b][i];
        float lo = wtT[ili * NWT + lane];
        float hi = wtT[ihi * NWT + lane];
        acc += (lo + alpha * (hi - lo)) * y_l[b][i];
      }
      acc *= 0.25f;  // mean over batch
    }
    lds_att[i][lane] = acc;
  }
  __syncthreads();

  float w0 = cw[0], w1 = cw[1], w2 = cw[2], w3 = cw[3], w4 = cw[4];
  float bias = cb[0];
#pragma unroll 4
  for (int i = wid; i < BLK; i += 8) {
    int t = t0 + i;
    if (t >= T) continue;  // wave-uniform
    float c = bias + lds_att[i][lane] * w0 + lds_att[i + 1][lane] * w1 +
              lds_att[i + 2][lane] * w2 + lds_att[i + 3][lane] * w3 +
              lds_att[i + 4][lane] * w4;
    float e = __expf(c);   // no max-subtract (shift-invariant, c bounded)
    float r0, r1, r2, r3;
    {
      unsigned st = ilh_l[0][i + 2];
      float alpha = alf_l[0][i + 2];
      float lo = wtT[(st & 0xffff) * NWT + lane], hi = wtT[(st >> 16) * NWT + lane];
      r0 = e * (lo + alpha * (hi - lo));
    }
    {
      unsigned st = ilh_l[1][i + 2];
      float alpha = alf_l[1][i + 2];
      float lo = wtT[(st & 0xffff) * NWT + lane], hi = wtT[(st >> 16) * NWT + lane];
      r1 = e * (lo + alpha * (hi - lo));
    }
    {
      unsigned st = ilh_l[2][i + 2];
      float alpha = alf_l[2][i + 2];
      float lo = wtT[(st & 0xffff) * NWT + lane], hi = wtT[(st >> 16) * NWT + lane];
      r2 = e * (lo + alpha * (hi - lo));
    }
    {
      unsigned st = ilh_l[3][i + 2];
      float alpha = alf_l[3][i + 2];
      float lo = wtT[(st & 0xffff) * NWT + lane], hi = wtT[(st >> 16) * NWT + lane];
      r3 = e * (lo + alpha * (hi - lo));
    }
    // 5 VALU-pipe DPP reductions (independent chains)
    float s0 = dpp_reduce_add(r0);
    float s1_ = dpp_reduce_add(r1);
    float s2_ = dpp_reduce_add(r2);
    float s3_ = dpp_reduce_add(r3);
    float ssum = dpp_reduce_add(e);
#if __has_builtin(__builtin_amdgcn_rcpf)
    float rc = __builtin_amdgcn_rcpf(ssum);
#else
    float rc = 1.0f / ssum;
#endif
    if (lane < BB) {
      float pv = lane == 0 ? s0 : lane == 1 ? s1_ : lane == 2 ? s2_ : s3_;
      out_l[lane][i] = pv * rc * amp_l[lane][i + 2];
    }
  }
  __syncthreads();

  // ---- Epilogue: coalesced stores (512 threads = 4b x 128t) ----
  {
    int b = threadIdx.x >> 7, toff = threadIdx.x & 127;
    int t = t0 + toff;
    if (t < T) out[(size_t)b * T + t] = out_l[b][toff];
  }
}

extern "C" void kernel_launch(void* const* d_in, const int* in_sizes, int n_in,
                              void* d_out, int out_size, void* d_ws, size_t ws_size,
                              hipStream_t stream) {
  const float* pitch = (const float*)d_in[0];
  const float* amp   = (const float*)d_in[1];
  const float* y     = (const float*)d_in[2];
  const float* wt    = (const float*)d_in[3];
  const float* cw    = (const float*)d_in[4];
  const float* cb    = (const float*)d_in[5];
  float* out = (float*)d_out;

  int BT = in_sizes[2];   // B*T
  int T = BT / BB;        // 132300
  int NB1 = (T + SBASE - 1) / SBASE;  // 8269

  float* ws   = (float*)d_ws;
  float* sarr = ws;
  float* wtT  = ws + (size_t)BT;
  float* s1g  = ws + (size_t)BT + NWT * LWT;

  // x=128 covers both NB1 (33 blocks used) and the transpose row (128 blocks)
  hipLaunchKernelGGL(scan_level0, dim3(128, BB + 1), dim3(256), 0, stream,
                     pitch, sarr, s1g, wt, wtT, T, NB1);
  hipLaunchKernelGGL(scan_upper, dim3(BB), dim3(1024), 0, stream, s1g, NB1);
  hipLaunchKernelGGL(fused_out, dim3((T + BLK - 1) / BLK), dim3(512), 0, stream,
                     pitch, sarr, s1g, y, amp, wtT, cw, cb, out, T, NB1);
}

// Round 15
// 62.749 us; speedup vs baseline: 1.0258x; 1.0258x over previous
//
#include <hip/hip_runtime.h>
#include <math.h>

#define LWT 512
#define NWT 64
#define BB 4
#define SBASE 16
#define BLK 64
#define HALO 68

// ws layout (floats): sarr [0,BT) | wtT [+32768) | s1g [+4*8320) | s2g [+4*544)

// XLA algsimp: x/44100 -> x * RN32(1/44100); *512 folds exactly (pow2), so
// increment = RN32(p * C), C = RN32(512/44100). asm barrier forces the product
// to be ROUNDED before the consuming add (blocks -ffp-contract=fast fusion).
#define INC_C ((float)(512.0 / 44100.0))

__device__ __forceinline__ float inc_mul(float p) {
  float v = p * INC_C;
  asm volatile("" : "+v"(v));
  return v;
}
__device__ __forceinline__ float inc_of(const float* p, int t) { return inc_mul(p[t]); }

// ---- Kernel A: level-0 local scans (fully parallel) + folded wt transpose ----
__global__ void __launch_bounds__(256) scan_level0(const float* __restrict__ pitch,
                                                   float* __restrict__ sarr,
                                                   float* __restrict__ s1g,
                                                   const float* __restrict__ wt,
                                                   float* __restrict__ wtT,
                                                   int T, int NB1) {
  if (blockIdx.y == BB) {  // folded transpose row
    int i = blockIdx.x * blockDim.x + threadIdx.x;
    if (i < NWT * LWT) {
      int n = i >> 9, c = i & 511;
      wtT[c * NWT + n] = wt[i];
    }
    return;
  }
  int k = blockIdx.x * blockDim.x + threadIdx.x;
  int b = blockIdx.y;
  if (k >= NB1) return;
  const float* prow = pitch + (size_t)b * T;
  float* srow = sarr + (size_t)b * T;
  int t0 = k * SBASE;
  float run = 0.0f;
  if (t0 + SBASE <= T) {
    const float4* p4 = reinterpret_cast<const float4*>(prow + t0);
    float4* s4o = reinterpret_cast<float4*>(srow + t0);
#pragma unroll
    for (int i = 0; i < 4; ++i) {
      float4 v = p4[i];
      float4 o;
      run += inc_mul(v.x); o.x = run;
      run += inc_mul(v.y); o.y = run;
      run += inc_mul(v.z); o.z = run;
      run += inc_mul(v.w); o.w = run;
      s4o[i] = o;
    }
  } else {
    for (int t = t0; t < T; ++t) { run += inc_of(prow, t); srow[t] = run; }
  }
  s1g[(size_t)b * NB1 + k] = run;
}

// ---- Kernel B1: level-1 local 16-scans of s1g in place (fully parallel) ----
// Each thread owns one 16-block: sequential prefix in place, total -> s2g.
__global__ void __launch_bounds__(256) scan_level1(float* __restrict__ s1g,
                                                   float* __restrict__ s2g,
                                                   int NB1, int NB2) {
  int k = blockIdx.x * blockDim.x + threadIdx.x;
  int b = blockIdx.y;
  if (k >= NB2) return;
  float* s1r = s1g + (size_t)b * NB1;
  int a0 = k * SBASE, a1 = a0 + SBASE < NB1 ? a0 + SBASE : NB1;
  float run = 0.0f;
  for (int a = a0; a < a1; ++a) { run += s1r[a]; s1r[a] = run; }
  s2g[(size_t)b * NB2 + k] = run;
}

// ---- Kernel B2: levels 2..4 + combine into s2g (tiny, one block) ----
// Per row: local 16-scans of s2 -> s3; s3 -> s4(seq); s3 += s4[k-1];
// s2 += s3[k-1]; write back. The s1 combine is folded into fused stage A.
__global__ void __launch_bounds__(256) scan_upper(float* __restrict__ s2g, int NB2) {
  __shared__ float s2[BB][544];
  __shared__ float s3[BB][48];
  __shared__ float s4[BB][16];
  int tid = threadIdx.x;
  const int NB3 = (NB2 + SBASE - 1) / SBASE;  // 33
  const int NB4 = (NB3 + SBASE - 1) / SBASE;  // 3
  for (int b = 0; b < BB; ++b)
    for (int a = tid; a < NB2; a += 256) s2[b][a] = s2g[(size_t)b * NB2 + a];
  __syncthreads();
  // level 2 (4 rows x 33 scans = 132 threads)
  if (tid < BB * NB3) {
    int b = tid / NB3, k = tid % NB3;
    int a0 = k * SBASE, a1 = a0 + SBASE < NB2 ? a0 + SBASE : NB2;
    float run = 0.0f;
    for (int a = a0; a < a1; ++a) { run += s2[b][a]; s2[b][a] = run; }
    s3[b][k] = run;
  }
  __syncthreads();
  // level 3 (4 rows x 3 scans)
  if (tid < BB * NB4) {
    int b = tid / NB4, k = tid % NB4;
    int a0 = k * SBASE, a1 = a0 + SBASE < NB3 ? a0 + SBASE : NB3;
    float run = 0.0f;
    for (int a = a0; a < a1; ++a) { run += s3[b][a]; s3[b][a] = run; }
    s4[b][k] = run;
  }
  __syncthreads();
  // level 4 sequential (NB4 <= 16)
  if (tid < BB) {
    int b = tid;
    float r = 0.0f;
    for (int a = 0; a < NB4; ++a) { r += s4[b][a]; s4[b][a] = r; }
  }
  __syncthreads();
  // combine s3 += s4[k-1]
  if (tid < BB * NB3) {
    int b = tid / NB3, a = tid % NB3;
    if (a >= SBASE) s3[b][a] = s3[b][a] + s4[b][a / SBASE - 1];
  }
  __syncthreads();
  // combine s2 += s3[k-1]; write back
  for (int b = 0; b < BB; ++b)
    for (int a = tid; a < NB2; a += 256) {
      float v = s2[b][a];
      if (a >= SBASE) v = v + s3[b][a / SBASE - 1];
      s2g[(size_t)b * NB2 + a] = v;
    }
}

// Wave64 reduction on the VALU pipe (DPP): xor1, xor2 (quad_perm),
// row_half_mirror, row_mirror, bcast15 (rows 1&3), bcast31 (rows 2&3);
// full sum in lanes 48-63; readlane(63) broadcasts.
__device__ __forceinline__ float dpp_reduce_add(float x) {
  x += __int_as_float(__builtin_amdgcn_update_dpp(0, __float_as_int(x), 0xB1, 0xf, 0xf, true));
  x += __int_as_float(__builtin_amdgcn_update_dpp(0, __float_as_int(x), 0x4E, 0xf, 0xf, true));
  x += __int_as_float(__builtin_amdgcn_update_dpp(0, __float_as_int(x), 0x141, 0xf, 0xf, true));
  x += __int_as_float(__builtin_amdgcn_update_dpp(0, __float_as_int(x), 0x140, 0xf, 0xf, true));
  x += __int_as_float(__builtin_amdgcn_update_dpp(0, __float_as_int(x), 0x142, 0xa, 0xf, true));
  x += __int_as_float(__builtin_amdgcn_update_dpp(0, __float_as_int(x), 0x143, 0xc, 0xf, true));
  return __int_as_float(__builtin_amdgcn_readlane(__float_as_int(x), 63));
}

// ---- Fused: s1-combine + finalize(idx) + att_pre + conv + softmax + einsum ----
// 256 threads, BLK=64. B-major conflict-free staging; stage A folds the ref's
// s1 += s2[k-1] combine (same two RN adds in ref order -> bit-identical).
__global__ void __launch_bounds__(256) fused_out(
    const float* __restrict__ pitch, const float* __restrict__ sarr,
    const float* __restrict__ s1g, const float* __restrict__ s2g,
    const float* __restrict__ y, const float* __restrict__ amp,
    const float* __restrict__ wtT, const float* __restrict__ cw,
    const float* __restrict__ cb, float* __restrict__ out,
    int T, int NB1, int NB2) {
  __shared__ float lds_att[HALO][64];     // 17.4 KB
  __shared__ unsigned ilh_l[BB][HALO];    // il | ih<<16
  __shared__ float alf_l[BB][HALO];
  __shared__ float y_l[BB][HALO];
  __shared__ float amp_l[BB][HALO];
  __shared__ float out_l[BB][BLK + 1];    // +1 pad: kills 4-way bank conflict
  int t0 = blockIdx.x * BLK;
  int wid = threadIdx.x >> 6, lane = threadIdx.x & 63;

  // ---- Stage A: wave = batch b, lane = halo index ----
  {
    int b = wid;
    for (int i = lane; i < HALO; i += 64) {
      int t = t0 - 2 + i;
      if (t >= 0 && t < T) {
        float S = sarr[(size_t)b * T + t];
        if (t >= SBASE) {
          int k1 = (t >> 4) - 1;
          float s1v = s1g[b * NB1 + k1];
          if (k1 >= SBASE) s1v = s1v + s2g[b * NB2 + (k1 >> 4) - 1];  // ref combine
          S = S + s1v;
        }
        float iv = S - inc_of(pitch, t);   // row-0 increment, folded constant
        // exact mod 512 (== fmodf+fixup bits; q exact pow2 scale, one fma rnd)
        float q = iv * (1.0f / 512.0f);
        float k = floorf(q);
        iv = fmaf(-k, 512.0f, iv);
        float fl = floorf(iv);
        float alpha = iv - fl;              // exact (Sterbenz)
        int ili = (int)fl; if (ili > 511) ili = 511;   // jnp.take clip
        int ihi = ((int)ceilf(iv)) & 511;              // ceil 512 wraps to 0
        ilh_l[b][i] = (unsigned)ili | ((unsigned)ihi << 16);
        alf_l[b][i] = alpha;
        y_l[b][i] = y[(size_t)b * T + t];
        amp_l[b][i] = amp[(size_t)b * T + t];
      }
    }
  }
  __syncthreads();

  // ---- Stage B: att_pre ----
  for (int i = wid; i < HALO; i += 4) {
    int t = t0 - 2 + i;
    float acc = 0.0f;
    if (t >= 0 && t < T) {
#pragma unroll
      for (int b = 0; b < BB; ++b) {
        unsigned st = ilh_l[b][i];
        int ili = st & 0xffff, ihi = st >> 16;
        float alpha = alf_l[b][i];
        float lo = wtT[ili * NWT + lane];
        float hi = wtT[ihi * NWT + lane];
        acc += (lo + alpha * (hi - lo)) * y_l[b][i];
      }
      acc *= 0.25f;  // mean over batch
    }
    lds_att[i][lane] = acc;
  }
  __syncthreads();

  float w0 = cw[0], w1 = cw[1], w2 = cw[2], w3 = cw[3], w4 = cw[4];
  float bias = cb[0];
#pragma unroll 4
  for (int i = wid; i < BLK; i += 4) {
    int t = t0 + i;
    if (t >= T) continue;  // wave-uniform
    float c = bias + lds_att[i][lane] * w0 + lds_att[i + 1][lane] * w1 +
              lds_att[i + 2][lane] * w2 + lds_att[i + 3][lane] * w3 +
              lds_att[i + 4][lane] * w4;
    float e = __expf(c);   // no max-subtract (shift-invariant, c bounded)
    float r0, r1, r2, r3;
    {
      unsigned st = ilh_l[0][i + 2];
      float alpha = alf_l[0][i + 2];
      float lo = wtT[(st & 0xffff) * NWT + lane], hi = wtT[(st >> 16) * NWT + lane];
      r0 = e * (lo + alpha * (hi - lo));
    }
    {
      unsigned st = ilh_l[1][i + 2];
      float alpha = alf_l[1][i + 2];
      float lo = wtT[(st & 0xffff) * NWT + lane], hi = wtT[(st >> 16) * NWT + lane];
      r1 = e * (lo + alpha * (hi - lo));
    }
    {
      unsigned st = ilh_l[2][i + 2];
      float alpha = alf_l[2][i + 2];
      float lo = wtT[(st & 0xffff) * NWT + lane], hi = wtT[(st >> 16) * NWT + lane];
      r2 = e * (lo + alpha * (hi - lo));
    }
    {
      unsigned st = ilh_l[3][i + 2];
      float alpha = alf_l[3][i + 2];
      float lo = wtT[(st & 0xffff) * NWT + lane], hi = wtT[(st >> 16) * NWT + lane];
      r3 = e * (lo + alpha * (hi - lo));
    }
    // 5 VALU-pipe DPP reductions (independent chains)
    float s0 = dpp_reduce_add(r0);
    float s1_ = dpp_reduce_add(r1);
    float s2_ = dpp_reduce_add(r2);
    float s3_ = dpp_reduce_add(r3);
    float ssum = dpp_reduce_add(e);
#if __has_builtin(__builtin_amdgcn_rcpf)
    float rc = __builtin_amdgcn_rcpf(ssum);
#else
    float rc = 1.0f / ssum;
#endif
    if (lane < BB) {
      float pv = lane == 0 ? s0 : lane == 1 ? s1_ : lane == 2 ? s2_ : s3_;
      out_l[lane][i] = pv * rc * amp_l[lane][i + 2];
    }
  }
  __syncthreads();

  // ---- Epilogue: coalesced stores (wave = batch, lane = t offset) ----
  {
    int b = wid;
    int t = t0 + lane;
    if (t < T) out[(size_t)b * T + t] = out_l[b][lane];
  }
}

extern "C" void kernel_launch(void* const* d_in, const int* in_sizes, int n_in,
                              void* d_out, int out_size, void* d_ws, size_t ws_size,
                              hipStream_t stream) {
  const float* pitch = (const float*)d_in[0];
  const float* amp   = (const float*)d_in[1];
  const float* y     = (const float*)d_in[2];
  const float* wt    = (const float*)d_in[3];
  const float* cw    = (const float*)d_in[4];
  const float* cb    = (const float*)d_in[5];
  float* out = (float*)d_out;

  int BT = in_sizes[2];   // B*T
  int T = BT / BB;        // 132300
  int NB1 = (T + SBASE - 1) / SBASE;    // 8269
  int NB2 = (NB1 + SBASE - 1) / SBASE;  // 517

  float* ws   = (float*)d_ws;
  float* sarr = ws;
  float* wtT  = ws + (size_t)BT;
  float* s1g  = ws + (size_t)BT + NWT * LWT;
  float* s2g  = s1g + (size_t)BB * NB1;

  hipLaunchKernelGGL(scan_level0, dim3(128, BB + 1), dim3(256), 0, stream,
                     pitch, sarr, s1g, wt, wtT, T, NB1);
  hipLaunchKernelGGL(scan_level1, dim3((NB2 + 255) / 256, BB), dim3(256), 0, stream,
                     s1g, s2g, NB1, NB2);
  hipLaunchKernelGGL(scan_upper, dim3(1), dim3(256), 0, stream, s2g, NB2);
  hipLaunchKernelGGL(fused_out, dim3((T + BLK - 1) / BLK), dim3(256), 0, stream,
                     pitch, sarr, s1g, s2g, y, amp, wtT, cw, cb, out, T, NB1, NB2);
}

// Round 16
// 55.711 us; speedup vs baseline: 1.1554x; 1.1263x over previous
//
#include <hip/hip_runtime.h>
#include <math.h>

#define LWT 512
#define NWT 64
#define BB 4
#define SBASE 16
#define BLK 32
#define HALO 36

// ws layout (floats): sarr [0,BT) | wtT [+32768) | s1g [+4*8320) | s2g [+4*544)

// XLA algsimp: x/44100 -> x * RN32(1/44100); *512 folds exactly (pow2), so
// increment = RN32(p * C), C = RN32(512/44100). asm barrier forces the product
// to be ROUNDED before the consuming add (blocks -ffp-contract=fast fusion).
#define INC_C ((float)(512.0 / 44100.0))

__device__ __forceinline__ float inc_mul(float p) {
  float v = p * INC_C;
  asm volatile("" : "+v"(v));
  return v;
}
__device__ __forceinline__ float inc_of(const float* p, int t) { return inc_mul(p[t]); }

// saddr-form load: uniform SGPR base + 32-bit per-lane byte offset (1 v_add).
__device__ __forceinline__ float wt_at(const float* wtT, unsigned byteoff) {
  return *reinterpret_cast<const float*>(reinterpret_cast<const char*>(wtT) + byteoff);
}

// ---- Kernel A: level-0 local scans (fully parallel) + folded wt transpose ----
__global__ void __launch_bounds__(256) scan_level0(const float* __restrict__ pitch,
                                                   float* __restrict__ sarr,
                                                   float* __restrict__ s1g,
                                                   const float* __restrict__ wt,
                                                   float* __restrict__ wtT,
                                                   int T, int NB1) {
  if (blockIdx.y == BB) {  // folded transpose row
    int i = blockIdx.x * blockDim.x + threadIdx.x;
    if (i < NWT * LWT) {
      int n = i >> 9, c = i & 511;
      wtT[c * NWT + n] = wt[i];
    }
    return;
  }
  int k = blockIdx.x * blockDim.x + threadIdx.x;
  int b = blockIdx.y;
  if (k >= NB1) return;
  const float* prow = pitch + (size_t)b * T;
  float* srow = sarr + (size_t)b * T;
  int t0 = k * SBASE;
  float run = 0.0f;
  if (t0 + SBASE <= T) {
    const float4* p4 = reinterpret_cast<const float4*>(prow + t0);
    float4* s4o = reinterpret_cast<float4*>(srow + t0);
#pragma unroll
    for (int i = 0; i < 4; ++i) {
      float4 v = p4[i];
      float4 o;
      run += inc_mul(v.x); o.x = run;
      run += inc_mul(v.y); o.y = run;
      run += inc_mul(v.z); o.z = run;
      run += inc_mul(v.w); o.w = run;
      s4o[i] = o;
    }
  } else {
    for (int t = t0; t < T; ++t) { run += inc_of(prow, t); srow[t] = run; }
  }
  s1g[(size_t)b * NB1 + k] = run;
}

// ---- Kernel B1: level-1 local 16-scans of s1g in place (fully parallel) ----
__global__ void __launch_bounds__(256) scan_level1(float* __restrict__ s1g,
                                                   float* __restrict__ s2g,
                                                   int NB1, int NB2) {
  int k = blockIdx.x * blockDim.x + threadIdx.x;
  int b = blockIdx.y;
  if (k >= NB2) return;
  float* s1r = s1g + (size_t)b * NB1;
  int a0 = k * SBASE, a1 = a0 + SBASE < NB1 ? a0 + SBASE : NB1;
  float run = 0.0f;
  for (int a = a0; a < a1; ++a) { run += s1r[a]; s1r[a] = run; }
  s2g[(size_t)b * NB2 + k] = run;
}

// ---- Kernel B2: levels 2..4 + combine into s2g (tiny, one block) ----
__global__ void __launch_bounds__(256) scan_upper(float* __restrict__ s2g, int NB2) {
  __shared__ float s2[BB][544];
  __shared__ float s3[BB][48];
  __shared__ float s4[BB][16];
  int tid = threadIdx.x;
  const int NB3 = (NB2 + SBASE - 1) / SBASE;  // 33
  const int NB4 = (NB3 + SBASE - 1) / SBASE;  // 3
  for (int b = 0; b < BB; ++b)
    for (int a = tid; a < NB2; a += 256) s2[b][a] = s2g[(size_t)b * NB2 + a];
  __syncthreads();
  if (tid < BB * NB3) {
    int b = tid / NB3, k = tid % NB3;
    int a0 = k * SBASE, a1 = a0 + SBASE < NB2 ? a0 + SBASE : NB2;
    float run = 0.0f;
    for (int a = a0; a < a1; ++a) { run += s2[b][a]; s2[b][a] = run; }
    s3[b][k] = run;
  }
  __syncthreads();
  if (tid < BB * NB4) {
    int b = tid / NB4, k = tid % NB4;
    int a0 = k * SBASE, a1 = a0 + SBASE < NB3 ? a0 + SBASE : NB3;
    float run = 0.0f;
    for (int a = a0; a < a1; ++a) { run += s3[b][a]; s3[b][a] = run; }
    s4[b][k] = run;
  }
  __syncthreads();
  if (tid < BB) {
    int b = tid;
    float r = 0.0f;
    for (int a = 0; a < NB4; ++a) { r += s4[b][a]; s4[b][a] = r; }
  }
  __syncthreads();
  if (tid < BB * NB3) {
    int b = tid / NB3, a = tid % NB3;
    if (a >= SBASE) s3[b][a] = s3[b][a] + s4[b][a / SBASE - 1];
  }
  __syncthreads();
  for (int b = 0; b < BB; ++b)
    for (int a = tid; a < NB2; a += 256) {
      float v = s2[b][a];
      if (a >= SBASE) v = v + s3[b][a / SBASE - 1];
      s2g[(size_t)b * NB2 + a] = v;
    }
}

// Wave64 reduction on the VALU pipe (DPP): xor1, xor2 (quad_perm),
// row_half_mirror, row_mirror, bcast15 (rows 1&3), bcast31 (rows 2&3);
// full sum in lanes 48-63; readlane(63) broadcasts.
__device__ __forceinline__ float dpp_reduce_add(float x) {
  x += __int_as_float(__builtin_amdgcn_update_dpp(0, __float_as_int(x), 0xB1, 0xf, 0xf, true));
  x += __int_as_float(__builtin_amdgcn_update_dpp(0, __float_as_int(x), 0x4E, 0xf, 0xf, true));
  x += __int_as_float(__builtin_amdgcn_update_dpp(0, __float_as_int(x), 0x141, 0xf, 0xf, true));
  x += __int_as_float(__builtin_amdgcn_update_dpp(0, __float_as_int(x), 0x140, 0xf, 0xf, true));
  x += __int_as_float(__builtin_amdgcn_update_dpp(0, __float_as_int(x), 0x142, 0xa, 0xf, true));
  x += __int_as_float(__builtin_amdgcn_update_dpp(0, __float_as_int(x), 0x143, 0xc, 0xf, true));
  return __int_as_float(__builtin_amdgcn_readlane(__float_as_int(x), 63));
}

// ---- Fused: s1-combine + finalize(idx) + att_pre + conv + softmax + einsum ----
// BLK=32, 12.6 KB LDS -> wave-capped occupancy (8 blocks/CU, 100%).
// Stage A stores PRE-SCALED byte offsets (il<<8) so every wtT access is a
// single v_add + saddr global load.
__global__ void __launch_bounds__(256) fused_out(
    const float* __restrict__ pitch, const float* __restrict__ sarr,
    const float* __restrict__ s1g, const float* __restrict__ s2g,
    const float* __restrict__ y, const float* __restrict__ amp,
    const float* __restrict__ wtT, const float* __restrict__ cw,
    const float* __restrict__ cb, float* __restrict__ out,
    int T, int NB1, int NB2) {
  __shared__ float lds_att[HALO][64];     // 9.2 KB
  __shared__ unsigned ilo_l[BB][HALO];    // byte offset il*256
  __shared__ unsigned ihi_l[BB][HALO];    // byte offset ih*256
  __shared__ float alf_l[BB][HALO];
  __shared__ float y_l[BB][HALO];
  __shared__ float amp_l[BB][HALO];
  __shared__ float out_l[BB][BLK + 1];    // +1 pad: conflict-free 4-lane store
  int t0 = blockIdx.x * BLK;
  int wid = threadIdx.x >> 6, lane = threadIdx.x & 63;
  unsigned lane4 = (unsigned)lane << 2;

  // ---- Stage A: wave = batch b, lane = halo index ----
  {
    int b = wid;
    for (int i = lane; i < HALO; i += 64) {
      int t = t0 - 2 + i;
      if (t >= 0 && t < T) {
        float S = sarr[(size_t)b * T + t];
        if (t >= SBASE) {
          int k1 = (t >> 4) - 1;
          float s1v = s1g[b * NB1 + k1];
          if (k1 >= SBASE) s1v = s1v + s2g[b * NB2 + (k1 >> 4) - 1];  // ref combine
          S = S + s1v;
        }
        float iv = S - inc_of(pitch, t);   // row-0 increment, folded constant
        // exact mod 512 (== fmodf+fixup bits; q exact pow2 scale, one fma rnd)
        float q = iv * (1.0f / 512.0f);
        float k = floorf(q);
        iv = fmaf(-k, 512.0f, iv);
        float fl = floorf(iv);
        float alpha = iv - fl;              // exact (Sterbenz)
        int ili = (int)fl; if (ili > 511) ili = 511;   // jnp.take clip
        int ihi = ((int)ceilf(iv)) & 511;              // ceil 512 wraps to 0
        ilo_l[b][i] = (unsigned)ili << 8;   // *NWT(64) * 4B
        ihi_l[b][i] = (unsigned)ihi << 8;
        alf_l[b][i] = alpha;
        y_l[b][i] = y[(size_t)b * T + t];
        amp_l[b][i] = amp[(size_t)b * T + t];
      }
    }
  }
  __syncthreads();

  // ---- Stage B: att_pre ----
  for (int i = wid; i < HALO; i += 4) {
    int t = t0 - 2 + i;
    float acc = 0.0f;
    if (t >= 0 && t < T) {
#pragma unroll
      for (int b = 0; b < BB; ++b) {
        float lo = wt_at(wtT, ilo_l[b][i] + lane4);
        float hi = wt_at(wtT, ihi_l[b][i] + lane4);
        float alpha = alf_l[b][i];
        acc += (lo + alpha * (hi - lo)) * y_l[b][i];
      }
      acc *= 0.25f;  // mean over batch
    }
    lds_att[i][lane] = acc;
  }
  __syncthreads();

  float w0 = cw[0], w1 = cw[1], w2 = cw[2], w3 = cw[3], w4 = cw[4];
  float bias = cb[0];
#pragma unroll 4
  for (int i = wid; i < BLK; i += 4) {
    int t = t0 + i;
    if (t >= T) continue;  // wave-uniform
    float c = bias + lds_att[i][lane] * w0 + lds_att[i + 1][lane] * w1 +
              lds_att[i + 2][lane] * w2 + lds_att[i + 3][lane] * w3 +
              lds_att[i + 4][lane] * w4;
    float e = __expf(c);   // no max-subtract (shift-invariant, c bounded)
    float r0, r1, r2, r3;
    {
      float lo = wt_at(wtT, ilo_l[0][i + 2] + lane4);
      float hi = wt_at(wtT, ihi_l[0][i + 2] + lane4);
      r0 = e * (lo + alf_l[0][i + 2] * (hi - lo));
    }
    {
      float lo = wt_at(wtT, ilo_l[1][i + 2] + lane4);
      float hi = wt_at(wtT, ihi_l[1][i + 2] + lane4);
      r1 = e * (lo + alf_l[1][i + 2] * (hi - lo));
    }
    {
      float lo = wt_at(wtT, ilo_l[2][i + 2] + lane4);
      float hi = wt_at(wtT, ihi_l[2][i + 2] + lane4);
      r2 = e * (lo + alf_l[2][i + 2] * (hi - lo));
    }
    {
      float lo = wt_at(wtT, ilo_l[3][i + 2] + lane4);
      float hi = wt_at(wtT, ihi_l[3][i + 2] + lane4);
      r3 = e * (lo + alf_l[3][i + 2] * (hi - lo));
    }
    // 5 VALU-pipe DPP reductions (independent chains)
    float s0 = dpp_reduce_add(r0);
    float s1_ = dpp_reduce_add(r1);
    float s2_ = dpp_reduce_add(r2);
    float s3_ = dpp_reduce_add(r3);
    float ssum = dpp_reduce_add(e);
#if __has_builtin(__builtin_amdgcn_rcpf)
    float rc = __builtin_amdgcn_rcpf(ssum);
#else
    float rc = 1.0f / ssum;
#endif
    if (lane < BB) {
      float pv = lane == 0 ? s0 : lane == 1 ? s1_ : lane == 2 ? s2_ : s3_;
      out_l[lane][i] = pv * rc * amp_l[lane][i + 2];
    }
  }
  __syncthreads();

  // ---- Epilogue: coalesced stores (wave = batch, lanes 0..BLK-1) ----
  {
    int b = wid;
    int t = t0 + lane;
    if (lane < BLK && t < T) out[(size_t)b * T + t] = out_l[b][lane];
  }
}

extern "C" void kernel_launch(void* const* d_in, const int* in_sizes, int n_in,
                              void* d_out, int out_size, void* d_ws, size_t ws_size,
                              hipStream_t stream) {
  const float* pitch = (const float*)d_in[0];
  const float* amp   = (const float*)d_in[1];
  const float* y     = (const float*)d_in[2];
  const float* wt    = (const float*)d_in[3];
  const float* cw    = (const float*)d_in[4];
  const float* cb    = (const float*)d_in[5];
  float* out = (float*)d_out;

  int BT = in_sizes[2];   // B*T
  int T = BT / BB;        // 132300
  int NB1 = (T + SBASE - 1) / SBASE;    // 8269
  int NB2 = (NB1 + SBASE - 1) / SBASE;  // 517

  float* ws   = (float*)d_ws;
  float* sarr = ws;
  float* wtT  = ws + (size_t)BT;
  float* s1g  = ws + (size_t)BT + NWT * LWT;
  float* s2g  = s1g + (size_t)BB * NB1;

  hipLaunchKernelGGL(scan_level0, dim3(128, BB + 1), dim3(256), 0, stream,
                     pitch, sarr, s1g, wt, wtT, T, NB1);
  hipLaunchKernelGGL(scan_level1, dim3((NB2 + 255) / 256, BB), dim3(256), 0, stream,
                     s1g, s2g, NB1, NB2);
  hipLaunchKernelGGL(scan_upper, dim3(1), dim3(256), 0, stream, s2g, NB2);
  hipLaunchKernelGGL(fused_out, dim3((T + BLK - 1) / BLK), dim3(256), 0, stream,
                     pitch, sarr, s1g, s2g, y, amp, wtT, cw, cb, out, T, NB1, NB2);
}

// Round 18
// 54.203 us; speedup vs baseline: 1.1875x; 1.0278x over previous
//
#include <hip/hip_runtime.h>
#include <math.h>

#define LWT 512
#define NWT 64
#define BB 4
#define SBASE 16
#define TPW 60          // output t's per wave (lanes 2..61; 0,1,62,63 are conv halo)
#define WPB 4           // waves per block
#define TPB (TPW * WPB) // 240 output t's per block
#define WSTRIDE 17      // lds_wt row stride (dwords); bank=(il*17+n)&31 spreads well

// ws layout (floats): sarr [0,BT) | wtT [+32768) | s1g [+4*8320) | s2g [+4*544)

// XLA algsimp: x/44100 -> x * RN32(1/44100); *512 folds exactly (pow2), so
// increment = RN32(p * C), C = RN32(512/44100). asm barrier forces the product
// to be ROUNDED before the consuming add (blocks -ffp-contract=fast fusion).
#define INC_C ((float)(512.0 / 44100.0))

__device__ __forceinline__ float inc_mul(float p) {
  float v = p * INC_C;
  asm volatile("" : "+v"(v));
  return v;
}
__device__ __forceinline__ float inc_of(const float* p, int t) { return inc_mul(p[t]); }

// ---- Kernel A: level-0 local scans (fully parallel) + folded wt transpose ----
__global__ void __launch_bounds__(256) scan_level0(const float* __restrict__ pitch,
                                                   float* __restrict__ sarr,
                                                   float* __restrict__ s1g,
                                                   const float* __restrict__ wt,
                                                   float* __restrict__ wtT,
                                                   int T, int NB1) {
  if (blockIdx.y == BB) {  // folded transpose row
    int i = blockIdx.x * blockDim.x + threadIdx.x;
    if (i < NWT * LWT) {
      int n = i >> 9, c = i & 511;
      wtT[c * NWT + n] = wt[i];
    }
    return;
  }
  int k = blockIdx.x * blockDim.x + threadIdx.x;
  int b = blockIdx.y;
  if (k >= NB1) return;
  const float* prow = pitch + (size_t)b * T;
  float* srow = sarr + (size_t)b * T;
  int t0 = k * SBASE;
  float run = 0.0f;
  if (t0 + SBASE <= T) {
    const float4* p4 = reinterpret_cast<const float4*>(prow + t0);
    float4* s4o = reinterpret_cast<float4*>(srow + t0);
#pragma unroll
    for (int i = 0; i < 4; ++i) {
      float4 v = p4[i];
      float4 o;
      run += inc_mul(v.x); o.x = run;
      run += inc_mul(v.y); o.y = run;
      run += inc_mul(v.z); o.z = run;
      run += inc_mul(v.w); o.w = run;
      s4o[i] = o;
    }
  } else {
    for (int t = t0; t < T; ++t) { run += inc_of(prow, t); srow[t] = run; }
  }
  s1g[(size_t)b * NB1 + k] = run;
}

// ---- Kernel B: merged level-1 scan + levels 2..4 + combine (1 block/row) ----
__global__ void __launch_bounds__(1024) scan_mid(float* __restrict__ s1g,
                                                 float* __restrict__ s2g,
                                                 int NB1, int NB2) {
  int b = blockIdx.x, tid = threadIdx.x;
  float* s1r = s1g + (size_t)b * NB1;
  __shared__ float s2[544];
  __shared__ float s3[48];
  __shared__ float s4[16];
  const int NB3 = (NB2 + SBASE - 1) / SBASE;  // 33
  const int NB4 = (NB3 + SBASE - 1) / SBASE;  // 3
  if (tid < NB2) {
    int a0 = tid * SBASE, a1 = a0 + SBASE < NB1 ? a0 + SBASE : NB1;
    float run = 0.0f;
    for (int a = a0; a < a1; ++a) { run += s1r[a]; s1r[a] = run; }
    s2[tid] = run;
  }
  __syncthreads();
  if (tid < NB3) {
    int a0 = tid * SBASE, a1 = a0 + SBASE < NB2 ? a0 + SBASE : NB2;
    float run = 0.0f;
    for (int a = a0; a < a1; ++a) { run += s2[a]; s2[a] = run; }
    s3[tid] = run;
  }
  __syncthreads();
  if (tid < NB4) {
    int a0 = tid * SBASE, a1 = a0 + SBASE < NB3 ? a0 + SBASE : NB3;
    float run = 0.0f;
    for (int a = a0; a < a1; ++a) { run += s3[a]; s3[a] = run; }
    s4[tid] = run;
  }
  __syncthreads();
  if (tid == 0) { float r = 0.0f; for (int a = 0; a < NB4; ++a) { r += s4[a]; s4[a] = r; } }
  __syncthreads();
  if (tid < NB3 && tid >= SBASE) s3[tid] = s3[tid] + s4[tid / SBASE - 1];
  __syncthreads();
  if (tid < NB2) {
    float v = s2[tid];
    if (tid >= SBASE) v = v + s3[tid / SBASE - 1];
    s2g[(size_t)b * NB2 + tid] = v;
  }
}

// ---- Fused, TRANSPOSED: lane = t, serial n; conv via __shfl (race-free) ----
// wt staged in LDS quarters [513 rows x 16 cols], row 512 = row 0 (phantom for
// the il=511 wrap; also makes hi ALWAYS base+WSTRIDE -> one ds_read2_b32 per
// (lo,hi)). alpha==0 cases give fma(0,hi-lo,lo)=lo regardless of hi: exact.
__global__ void __launch_bounds__(256) fused_out(
    const float* __restrict__ pitch, const float* __restrict__ sarr,
    const float* __restrict__ s1g, const float* __restrict__ s2g,
    const float* __restrict__ y, const float* __restrict__ amp,
    const float* __restrict__ wtT, const float* __restrict__ cw,
    const float* __restrict__ cb, float* __restrict__ out,
    int T, int NB1, int NB2) {
  __shared__ float lds_wt[513 * WSTRIDE];  // 34.9 KB
  int wid = threadIdx.x >> 6, lane = threadIdx.x & 63;
  int tw = blockIdx.x * TPB + wid * TPW;  // wave's first output t
  int t = tw - 2 + lane;                  // this lane's t (incl. halo lanes)

  // ---- Stage A: per-lane idx finalize for all 4 batches (bit-identical DAG) ----
  bool valid = (t >= 0 && t < T);
  int loi0 = 0, loi1 = 0, loi2 = 0, loi3 = 0;
  float alf[BB] = {0.f, 0.f, 0.f, 0.f};
  float yv[BB] = {0.f, 0.f, 0.f, 0.f};   // 0 outside [0,T): conv zero-pad
  float av[BB] = {0.f, 0.f, 0.f, 0.f};
  if (valid) {
#pragma unroll
    for (int b = 0; b < BB; ++b) {
      float S = sarr[(size_t)b * T + t];
      if (t >= SBASE) {
        int k1 = (t >> 4) - 1;
        float s1v = s1g[b * NB1 + k1];
        if (k1 >= SBASE) s1v = s1v + s2g[b * NB2 + (k1 >> 4) - 1];  // ref combine
        S = S + s1v;
      }
      float iv = S - inc_of(pitch, t);   // row-0 increment, folded constant
      // exact mod 512 (== fmodf+fixup bits; q exact pow2 scale, one fma rnd)
      float q = iv * (1.0f / 512.0f);
      float k = floorf(q);
      iv = fmaf(-k, 512.0f, iv);
      float fl = floorf(iv);
      float alpha = iv - fl;              // exact (Sterbenz)
      int ili = (int)fl; if (ili > 511) ili = 511;   // jnp.take clip
      int lo = ili * WSTRIDE;
      if (b == 0) loi0 = lo;
      else if (b == 1) loi1 = lo;
      else if (b == 2) loi2 = lo;
      else loi3 = lo;
      alf[b] = alpha;
      yv[b] = y[(size_t)b * T + t];
      av[b] = amp[(size_t)b * T + t];
    }
  }

  float w0 = cw[0], w1 = cw[1], w2 = cw[2], w3 = cw[3], w4 = cw[4];
  float bias = cb[0];
  float r0 = 0.f, r1 = 0.f, r2 = 0.f, r3 = 0.f, ssum = 0.f;

  for (int h = 0; h < 4; ++h) {
    __syncthreads();  // all waves done reading previous quarter
    // stage wt cols n = h*16 .. h*16+15 (513 rows; row 512 <- row 0)
    {
      const float4* w4p = reinterpret_cast<const float4*>(wtT);
      for (int idx = threadIdx.x; idx < 513 * 4; idx += 256) {
        int c = idx >> 2, k = idx & 3;
        int csrc = (c == 512) ? 0 : c;
        float4 v = w4p[csrc * 16 + h * 4 + k];
        int base = c * WSTRIDE + k * 4;
        lds_wt[base + 0] = v.x;
        lds_wt[base + 1] = v.y;
        lds_wt[base + 2] = v.z;
        lds_wt[base + 3] = v.w;
      }
    }
    __syncthreads();
#pragma unroll
    for (int n = 0; n < 16; ++n) {
      int b0 = loi0 + n, b1 = loi1 + n, b2 = loi2 + n, b3 = loi3 + n;
      float lo0 = lds_wt[b0], hi0 = lds_wt[b0 + WSTRIDE];
      float lo1 = lds_wt[b1], hi1 = lds_wt[b1 + WSTRIDE];
      float lo2 = lds_wt[b2], hi2 = lds_wt[b2 + WSTRIDE];
      float lo3 = lds_wt[b3], hi3 = lds_wt[b3 + WSTRIDE];
      float wv0 = lo0 + alf[0] * (hi0 - lo0);
      float wv1 = lo1 + alf[1] * (hi1 - lo1);
      float wv2 = lo2 + alf[2] * (hi2 - lo2);
      float wv3 = lo3 + alf[3] * (hi3 - lo3);
      float acc = wv0 * yv[0];
      acc += wv1 * yv[1];
      acc += wv2 * yv[2];
      acc += wv3 * yv[3];
      acc *= 0.25f;                       // att_pre(t_lane) for this n
      // conv5 via register shuffles (halo lanes feed the edges; no LDS race)
      float am2 = __shfl(acc, lane - 2);
      float am1 = __shfl(acc, lane - 1);
      float ap1 = __shfl(acc, lane + 1);
      float ap2 = __shfl(acc, lane + 2);
      float c0 = bias + am2 * w0 + am1 * w1 + acc * w2 + ap1 * w3 + ap2 * w4;
      float e = __expf(c0);  // no max-subtract (shift-invariant; c bounded)
      r0 += e * wv0;
      r1 += e * wv1;
      r2 += e * wv2;
      r3 += e * wv3;
      ssum += e;
    }
  }

  // lanes 2..61 hold valid conv outputs; halo lanes (0,1,62,63) discarded
  if (lane >= 2 && lane < 62 && t < T) {
#if __has_builtin(__builtin_amdgcn_rcpf)
    float rc = __builtin_amdgcn_rcpf(ssum);
#else
    float rc = 1.0f / ssum;
#endif
    out[(size_t)0 * T + t] = r0 * rc * av[0];
    out[(size_t)1 * T + t] = r1 * rc * av[1];
    out[(size_t)2 * T + t] = r2 * rc * av[2];
    out[(size_t)3 * T + t] = r3 * rc * av[3];
  }
}

extern "C" void kernel_launch(void* const* d_in, const int* in_sizes, int n_in,
                              void* d_out, int out_size, void* d_ws, size_t ws_size,
                              hipStream_t stream) {
  const float* pitch = (const float*)d_in[0];
  const float* amp   = (const float*)d_in[1];
  const float* y     = (const float*)d_in[2];
  const float* wt    = (const float*)d_in[3];
  const float* cw    = (const float*)d_in[4];
  const float* cb    = (const float*)d_in[5];
  float* out = (float*)d_out;

  int BT = in_sizes[2];   // B*T
  int T = BT / BB;        // 132300
  int NB1 = (T + SBASE - 1) / SBASE;    // 8269
  int NB2 = (NB1 + SBASE - 1) / SBASE;  // 517

  float* ws   = (float*)d_ws;
  float* sarr = ws;
  float* wtT  = ws + (size_t)BT;
  float* s1g  = ws + (size_t)BT + NWT * LWT;
  float* s2g  = s1g + (size_t)BB * NB1;

  hipLaunchKernelGGL(scan_level0, dim3(128, BB + 1), dim3(256), 0, stream,
                     pitch, sarr, s1g, wt, wtT, T, NB1);
  hipLaunchKernelGGL(scan_mid, dim3(BB), dim3(1024), 0, stream, s1g, s2g, NB1, NB2);
  hipLaunchKernelGGL(fused_out, dim3((T + TPB - 1) / TPB), dim3(256), 0, stream,
                     pitch, sarr, s1g, s2g, y, amp, wtT, cw, cb, out, T, NB1, NB2);
}